// Round 9
// baseline (29.317 us; speedup 1.0000x reference)
//
#include <hip/hip_runtime.h>
#include <math.h>

// LearnedDRoPEEnergy: B=16, K=256, H=W=64, T=1.0
// R9 = R8 with ONE change: pack blocks are 1024 threads (16 waves/CU instead
// of 4) to hide HBM latency over the same fully-sequential 256KB sweeps.
#define NPOS 65536
#define HWSZ 4096

typedef float floatx4 __attribute__((ext_vector_type(4)));

// 8 representative offsets (other 8 are negatives; d and gate symmetric,
// torus sum translation-invariant -> x2). Verified R2/R4-R8.
__device__ __constant__ int c_dy8[8] = {-1, 0, -1, -1, -2,  0, -2, -2};
__device__ __constant__ int c_dx8[8] = { 0,-1, -1,  1,  0, -2, -2,  2};

// Kernel A: pack. Block beta = b*16 + q owns 16 CONSECUTIVE k-planes
// (k = 16q..16q+15) = one unbroken 256 KB region of z. 1024 threads: thread
// covers 4 consecutive positions across all 16 planes (j outer -> ascending
// addresses). Register transpose into 4 u16 accumulators, one uint2 store.
// Output layout: pack16[g][pos], g = b*16+q, u16 per (g,pos), 2 MB total.
__global__ __launch_bounds__(1024) void pack_kernel(const float* __restrict__ z,
                                                    unsigned* __restrict__ packu32,
                                                    float* __restrict__ out) {
    int tid = threadIdx.x;                      // 0..1023
    unsigned beta = blockIdx.x;                 // 0..255 = b*16 + q
    const float* base = z + ((size_t)beta << 16);   // beta * 16*4096 floats
    unsigned a0 = 0, a1 = 0, a2 = 0, a3 = 0;
#pragma unroll
    for (int j = 0; j < 16; ++j) {              // plane within group (bit j)
        floatx4 v = __builtin_nontemporal_load(
            (const floatx4*)(base + (j << 12) + (tid << 2)));
        unsigned bit = 1u << j;
        if (v.x != 0.0f) a0 |= bit;
        if (v.y != 0.0f) a1 |= bit;
        if (v.z != 0.0f) a2 |= bit;
        if (v.w != 0.0f) a3 |= bit;
    }
    // pos = tid*4 + c; store (c0|c1<<16, c2|c3<<16) as uint2, 8B/lane coalesced
    unsigned* dst = packu32 + ((size_t)beta << 11);   // beta * 4096 u16
    *(uint2*)(dst + (tid << 1)) = make_uint2(a0 | (a1 << 16), a2 | (a3 << 16));
    if (beta == 0 && tid < 16) out[tid] = 0.0f;
}

// Kernel B: identical to R8 (verified absmax=0): 256 blocks x 256, thread =
// one position, in-kernel byte-LUT, 8 offsets x2 symmetry, q-major u16 loads.
__global__ __launch_bounds__(256) void energy_kernel(const unsigned short* __restrict__ p16,
                                                     const float* __restrict__ w_logit,
                                                     const float* __restrict__ tau_p,
                                                     float* __restrict__ out) {
    __shared__ float wtab[32 * 256];   // 32 KB byte-LUT: wtab[p][v], p = k/8
    __shared__ float red[4];

    int tid = threadIdx.x;
    {   // build LUT: thread covers (p = tid>>3, v = (tid&7)*32 .. +31)
        int p = tid >> 3;
        int vbase = (tid & 7) * 32;
        float wv[8];
#pragma unroll
        for (int j = 0; j < 8; ++j) {
            float x = w_logit[p * 8 + j];
            wv[j] = log1pf(expf(x));   // softplus, fp32
        }
        for (int v = vbase; v < vbase + 32; ++v) {
            float s = 0.0f;
#pragma unroll
            for (int j = 0; j < 8; ++j) s += ((v >> j) & 1) ? wv[j] : 0.0f;
            wtab[p * 256 + v] = s;
        }
    }
    __syncthreads();

    float tau = tau_p[0];
    int pos = blockIdx.x * 256 + tid;            // one thread per position
    int b  = pos >> 12;
    int hw = pos & 4095;
    int h  = hw >> 6;
    int w  = hw & 63;

    const unsigned short* pb = p16 + ((size_t)b << 16);  // b's 16 groups * 4096

    unsigned cw[16];                             // center words, loaded once
#pragma unroll
    for (int q = 0; q < 16; ++q) cw[q] = pb[(q << 12) + hw];

    float e = 0.0f;
#pragma unroll
    for (int o = 0; o < 8; ++o) {
        int h2 = (h + c_dy8[o]) & 63;
        int w2 = (w + c_dx8[o]) & 63;
        int hw2 = (h2 << 6) | w2;
        float d0 = 0.0f, d1 = 0.0f;
#pragma unroll
        for (int q = 0; q < 16; ++q) {
            unsigned x = cw[q] ^ (unsigned)pb[(q << 12) + hw2];  // u16 XOR
            d0 += wtab[(2 * q + 0) * 256 + (x & 255)];
            d1 += wtab[(2 * q + 1) * 256 + (x >> 8)];
        }
        float d = d0 + d1;
        // gate*d = d / (1 + exp(d - tau)); exp overflow -> inf -> 0, correct
        e += d / (1.0f + expf(d - tau));
    }

    // block reduction (b uniform per block); x2 for symmetry
#pragma unroll
    for (int s = 32; s > 0; s >>= 1) e += __shfl_down(e, s, 64);
    int lane = tid & 63, wv = tid >> 6;
    if (lane == 0) red[wv] = e;
    __syncthreads();
    if (tid == 0) {
        float s = red[0] + red[1] + red[2] + red[3];
        atomicAdd(out + b, 2.0f * s);
    }
}

extern "C" void kernel_launch(void* const* d_in, const int* in_sizes, int n_in,
                              void* d_out, int out_size, void* d_ws, size_t ws_size,
                              hipStream_t stream) {
    const float* z       = (const float*)d_in[0];   // (B,K,H,W) fp32 0/1
    const float* w_logit = (const float*)d_in[1];   // (K,)
    const float* tau     = (const float*)d_in[2];   // scalar
    float* out = (float*)d_out;                     // (B,)
    unsigned* packu32 = (unsigned*)d_ws;            // 2 MB, q-major u16 layout

    hipLaunchKernelGGL(pack_kernel, dim3(256), dim3(1024), 0, stream,
                       z, packu32, out);
    hipLaunchKernelGGL(energy_kernel, dim3(256), dim3(256), 0, stream,
                       (const unsigned short*)packu32, w_logit, tau, out);
}